// Round 8
// baseline (699.687 us; speedup 1.0000x reference)
//
#include <hip/hip_runtime.h>

typedef __attribute__((ext_vector_type(8))) short bf16x8;
typedef __attribute__((ext_vector_type(4))) float f32x4;

#define AS1 __attribute__((address_space(1)))
#define AS3 __attribute__((address_space(3)))

#if defined(__has_builtin)
#  if __has_builtin(__builtin_amdgcn_exp2f)
#    define EXP2F(x) __builtin_amdgcn_exp2f(x)
#  endif
#endif
#ifndef EXP2F
#  define EXP2F(x) __builtin_exp2f(x)
#endif

__device__ __forceinline__ unsigned short f2bf(float f) {
    union { float f; unsigned u; } v; v.f = f;
    unsigned r = v.u + 0x7fffu + ((v.u >> 16) & 1u);   // RNE
    return (unsigned short)(r >> 16);
}

// Async 16B/lane global->LDS DMA. lds dst must be wave-uniform base (+lane*16).
__device__ __forceinline__ void dma16(const void* g, void* l) {
    __builtin_amdgcn_global_load_lds((const AS1 unsigned int*)g,
                                     (AS3 unsigned int*)l, 16, 0, 0);
}

// fp32 -> bf16 bulk convert, up to 3 regions, optional scale. 8 elems/thread.
__global__ __launch_bounds__(256) void convert_regions(
    const float* __restrict__ s0, unsigned short* __restrict__ d0, int n0, float c0,
    const float* __restrict__ s1, unsigned short* __restrict__ d1, int n1, float c1,
    const float* __restrict__ s2, unsigned short* __restrict__ d2, int n2, float c2)
{
    long long e = ((long long)blockIdx.x * 256 + threadIdx.x) * 8;
    const float* s; unsigned short* d; float sc;
    if (e < n0) { s = s0; d = d0; sc = c0; }
    else { e -= n0;
    if (e < n1) { s = s1; d = d1; sc = c1; }
    else { e -= n1;
    if (e < n2) { s = s2; d = d2; sc = c2; } else return; } }
    const float4 f0 = *(const float4*)(s + e);
    const float4 f1 = *(const float4*)(s + e + 4);
    union { unsigned short u[8]; uint4 q; } t;
    t.u[0]=f2bf(f0.x*sc); t.u[1]=f2bf(f0.y*sc); t.u[2]=f2bf(f0.z*sc); t.u[3]=f2bf(f0.w*sc);
    t.u[4]=f2bf(f1.x*sc); t.u[5]=f2bf(f1.y*sc); t.u[6]=f2bf(f1.z*sc); t.u[7]=f2bf(f1.w*sc);
    *(uint4*)(d + e) = t.q;
}

// ---------------------------------------------------------------------------
// GEMM: C = A[M,K] * B[N,K]^T (+bias). 128x128 tile, BK=64, 4 waves (2x2),
// 4x4 16x16x32 MFMA/wave, bf16 operands via global_load_lds, XOR-swizzled
// unpadded LDS. __launch_bounds__(256,4): VGPR<=128 -> 4 blocks/CU for
// latency hiding across the staging barrier.
// CM: 0 = fp32 C0[M,N] + bias.
//     1 = fused QKV epilogue over N=3072: cols 0..1023 -> Q [bh][n][e] (C0),
//         1024..2047 -> K [bh][n][e] (C1), 2048..3071 -> V^T [bh][e][n] (C2).
//         V-blocks compute mfma(bF,aF) (transposed tile) so stores coalesce.
// ---------------------------------------------------------------------------
template<int CM>
__global__ __launch_bounds__(256, 4) void gemm128(
    const unsigned short* __restrict__ A, const unsigned short* __restrict__ B,
    void* __restrict__ C0, void* __restrict__ C1, void* __restrict__ C2,
    const float* __restrict__ bias, int M, int N, int K)
{
    __shared__ __align__(16) unsigned short As[128 * 64];
    __shared__ __align__(16) unsigned short Bs[128 * 64];

    const int tid  = threadIdx.x;
    const int wq   = tid >> 6;
    const int lane = tid & 63;
    const int l16  = lane & 15;
    const int quad = lane >> 4;
    const int m0   = blockIdx.x * 128;
    const int n0   = blockIdx.y * 128;
    const int lr   = lane >> 3;
    const int cs   = lane & 7;
    const bool vswap = (CM == 1) && (n0 >= 2048);

    f32x4 acc[4][4];
#pragma unroll
    for (int mt = 0; mt < 4; ++mt)
#pragma unroll
        for (int nt = 0; nt < 4; ++nt) acc[mt][nt] = (f32x4){0.f, 0.f, 0.f, 0.f};

    for (int kk = 0; kk < K; kk += 64) {
        __syncthreads();
#pragma unroll
        for (int i = 0; i < 4; ++i) {
            const int rr = (wq * 4 + i) * 8 + lr;
            const int cg = cs ^ (rr & 7);
            dma16(A + (size_t)(m0 + rr) * K + kk + cg * 8, As + (wq * 4 + i) * 512);
            dma16(B + (size_t)(n0 + rr) * K + kk + cg * 8, Bs + (wq * 4 + i) * 512);
        }
        __syncthreads();

#pragma unroll
        for (int ch = 0; ch < 2; ++ch) {
            const int swz = (((ch * 4 + quad) ^ (l16 & 7)) * 8);
            bf16x8 aF[4], bF[4];
#pragma unroll
            for (int mt = 0; mt < 4; ++mt)
                aF[mt] = *(const bf16x8*)(As + ((wq >> 1) * 64 + mt * 16 + l16) * 64 + swz);
#pragma unroll
            for (int nt = 0; nt < 4; ++nt)
                bF[nt] = *(const bf16x8*)(Bs + ((wq & 1) * 64 + nt * 16 + l16) * 64 + swz);
            if (vswap) {
#pragma unroll
                for (int mt = 0; mt < 4; ++mt)
#pragma unroll
                    for (int nt = 0; nt < 4; ++nt)
                        acc[mt][nt] = __builtin_amdgcn_mfma_f32_16x16x32_bf16(
                            bF[nt], aF[mt], acc[mt][nt], 0, 0, 0);
            } else {
#pragma unroll
                for (int mt = 0; mt < 4; ++mt)
#pragma unroll
                    for (int nt = 0; nt < 4; ++nt)
                        acc[mt][nt] = __builtin_amdgcn_mfma_f32_16x16x32_bf16(
                            aF[mt], bF[nt], acc[mt][nt], 0, 0, 0);
            }
        }
    }

    const int wr = wq >> 1, wc = wq & 1;
    if (CM == 0) {
#pragma unroll
        for (int mt = 0; mt < 4; ++mt)
#pragma unroll
        for (int nt = 0; nt < 4; ++nt) {
            const int coln = n0 + wc * 64 + nt * 16 + l16;
            const float bv = bias ? bias[coln] : 0.f;
#pragma unroll
            for (int r = 0; r < 4; ++r) {
                const int rowm = m0 + wr * 64 + mt * 16 + quad * 4 + r;
                ((float*)C0)[(size_t)rowm * N + coln] = acc[mt][nt][r] + bv;
            }
        }
    } else if (!vswap) {
        // Q (cols<1024) / K (1024..2047): [bh][n][e]
#pragma unroll
        for (int mt = 0; mt < 4; ++mt)
#pragma unroll
        for (int nt = 0; nt < 4; ++nt) {
            const int coln = n0 + wc * 64 + nt * 16 + l16;
            unsigned short* dst = (coln < 1024) ? (unsigned short*)C0 : (unsigned short*)C1;
            const int h = (coln >> 6) & 15, e = coln & 63;
#pragma unroll
            for (int r = 0; r < 4; ++r) {
                const int rowm = m0 + wr * 64 + mt * 16 + quad * 4 + r;
                const int b = rowm >> 11, n = rowm & 2047;
                dst[(((size_t)(b * 16 + h) * 2048 + n) << 6) + e] = f2bf(acc[mt][nt][r]);
            }
        }
    } else {
        // V^T: acc holds transposed tile; rows = V-cols (e), cols = tokens.
#pragma unroll
        for (int mt = 0; mt < 4; ++mt)
#pragma unroll
        for (int nt = 0; nt < 4; ++nt) {
#pragma unroll
            for (int r = 0; r < 4; ++r) {
                const int eg = n0 + wc * 64 + nt * 16 + quad * 4 + r;  // 2048..3071
                const int h = (eg >> 6) - 32, e = eg & 63;
                const int rowm = m0 + wr * 64 + mt * 16 + l16;
                const int b = rowm >> 11, n = rowm & 2047;
                ((unsigned short*)C2)[((size_t)(b * 16 + h) * 64 + e) * 2048 + n] =
                    f2bf(acc[mt][nt][r]);
            }
        }
    }
}

// ---------------------------------------------------------------------------
// Flash attention. Q,K: [bh][n][e] bf16 (Q pre-scaled by 0.125*log2e);
// V: [bh][e][n] bf16. O: [b*n][1024] bf16.
// Block = 256 q-rows (4 waves x 64 q as 4 sub-tiles of 16): halves K/V
// staging vs 128-q blocks and doubles MFMA per staged byte (262 FLOP/B).
// S^T = K*Q^T; raw v_exp_f32; P trunc-packed (v_perm); denom l on the MFMA
// pipe (P x ones); Ps wave-private (no barrier); K/Vt via global_load_lds.
// ---------------------------------------------------------------------------
__global__ __launch_bounds__(256, 2) void attn_kernel(
    const unsigned short* __restrict__ Q, const unsigned short* __restrict__ K,
    const unsigned short* __restrict__ V, unsigned short* __restrict__ O)
{
    __shared__ __align__(16) unsigned short Ks[64 * 64];
    __shared__ __align__(16) unsigned short Vt[64 * 64];
    __shared__ __align__(16) unsigned short Ps[4 * 64 * 72];

    const int tid  = threadIdx.x;
    const int q0   = blockIdx.x * 256;
    const int bh   = blockIdx.y;
    const int wq   = tid >> 6;
    const int lane = tid & 63;
    const int l16  = lane & 15;
    const int quad = lane >> 4;
    const int lr   = lane >> 3;
    const int cs   = lane & 7;

    const unsigned short* Qg = Q + (size_t)bh * 2048 * 64;
    const unsigned short* Kg = K + (size_t)bh * 2048 * 64;
    const unsigned short* Vg = V + (size_t)bh * 64 * 2048;

    bf16x8 bQ[4][2];
#pragma unroll
    for (int sub = 0; sub < 4; ++sub)
#pragma unroll
        for (int ch = 0; ch < 2; ++ch)
            bQ[sub][ch] = *(const bf16x8*)(Qg + (size_t)(q0 + wq * 64 + sub * 16 + l16) * 64
                                           + ch * 32 + quad * 8);

    bf16x8 ones;
#pragma unroll
    for (int i = 0; i < 8; ++i) ones[i] = (short)0x3F80;  // bf16 1.0

    f32x4 o[4][4], lf[4];
#pragma unroll
    for (int s = 0; s < 4; ++s) {
        lf[s] = (f32x4){0.f, 0.f, 0.f, 0.f};
#pragma unroll
        for (int e = 0; e < 4; ++e) o[s][e] = (f32x4){0.f, 0.f, 0.f, 0.f};
    }

    unsigned short* Psw = Ps + wq * 64 * 72;

    for (int kt = 0; kt < 32; ++kt) {
        const int key0 = kt * 64;
        __syncthreads();
#pragma unroll
        for (int i = 0; i < 4; ++i) {
            const int j  = wq * 4 + i;
            const int rr = (j & 7) * 8 + lr;
            const int cg = cs ^ (rr & 7);
            if (j < 8)
                dma16(Kg + (size_t)(key0 + rr) * 64 + cg * 8, Ks + (j & 7) * 512);
            else
                dma16(Vg + (size_t)rr * 2048 + key0 + cg * 8, Vt + (j & 7) * 512);
        }
        __syncthreads();

        // S^T = K Q^T : D[m=key][n=q]  (logits pre-scaled via Q)
        f32x4 s[4][4];
#pragma unroll
        for (int sub = 0; sub < 4; ++sub)
#pragma unroll
            for (int c = 0; c < 4; ++c) s[sub][c] = (f32x4){0.f, 0.f, 0.f, 0.f};
#pragma unroll
        for (int ch = 0; ch < 2; ++ch) {
            const int swz = ((ch * 4 + quad) ^ (l16 & 7)) * 8;
#pragma unroll
            for (int c = 0; c < 4; ++c) {
                const bf16x8 aK = *(const bf16x8*)(Ks + (c * 16 + l16) * 64 + swz);
#pragma unroll
                for (int sub = 0; sub < 4; ++sub)
                    s[sub][c] = __builtin_amdgcn_mfma_f32_16x16x32_bf16(
                        aK, bQ[sub][ch], s[sub][c], 0, 0, 0);
            }
        }

        // p = 2^s (raw v_exp_f32); trunc-pack pairs with v_perm into Ps.
#pragma unroll
        for (int sub = 0; sub < 4; ++sub) {
#pragma unroll
            for (int c = 0; c < 4; ++c) {
                const float p0 = EXP2F(s[sub][c][0]);
                const float p1 = EXP2F(s[sub][c][1]);
                const float p2 = EXP2F(s[sub][c][2]);
                const float p3 = EXP2F(s[sub][c][3]);
                uint2 pk;
                pk.x = __builtin_amdgcn_perm(__float_as_uint(p1), __float_as_uint(p0), 0x07060302);
                pk.y = __builtin_amdgcn_perm(__float_as_uint(p3), __float_as_uint(p2), 0x07060302);
                *(uint2*)(Psw + (sub * 16 + l16) * 72 + c * 16 + quad * 4) = pk;
            }
        }
        // Ps wave-private: compiler lgkmcnt covers RAW; no barrier.

        // O += P V ; l += P 1 (denominator on the MFMA pipe).
#pragma unroll
        for (int cc = 0; cc < 2; ++cc) {
            const int swz = ((cc * 4 + quad) ^ (l16 & 7)) * 8;
            bf16x8 aP[4];
#pragma unroll
            for (int sub = 0; sub < 4; ++sub) {
                aP[sub] = *(const bf16x8*)(Psw + (sub * 16 + l16) * 72 + cc * 32 + quad * 8);
                lf[sub] = __builtin_amdgcn_mfma_f32_16x16x32_bf16(aP[sub], ones, lf[sub], 0, 0, 0);
            }
#pragma unroll
            for (int et = 0; et < 4; ++et) {
                const bf16x8 bV = *(const bf16x8*)(Vt + (et * 16 + l16) * 64 + swz);
#pragma unroll
                for (int sub = 0; sub < 4; ++sub)
                    o[sub][et] = __builtin_amdgcn_mfma_f32_16x16x32_bf16(
                        aP[sub], bV, o[sub][et], 0, 0, 0);
            }
        }
    }

    // l sits in C-layout: lf[sub][r] is the denom for q-row quad*4+r (all l16).
    const int bb = bh >> 4, hh = bh & 15;
#pragma unroll
    for (int sub = 0; sub < 4; ++sub) {
#pragma unroll
        for (int r = 0; r < 4; ++r) {
            const float linv = 1.0f / lf[sub][r];
            const int qrow = q0 + wq * 64 + sub * 16 + quad * 4 + r;
#pragma unroll
            for (int et = 0; et < 4; ++et) {
                O[(size_t)(bb * 2048 + qrow) * 1024 + hh * 64 + et * 16 + l16] =
                    f2bf(o[sub][et][r] * linv);
            }
        }
    }
}

extern "C" void kernel_launch(void* const* d_in, const int* in_sizes, int n_in,
                              void* d_out, int out_size, void* d_ws, size_t ws_size,
                              hipStream_t stream) {
    const float* x     = (const float*)d_in[0];
    const float* w_q   = (const float*)d_in[1];
    const float* w_kv  = (const float*)d_in[2];
    const float* w_out = (const float*)d_in[3];
    const float* b_out = (const float*)d_in[4];
    const float CEXP = 0.125f * 1.44269504f;   // attn scale * log2(e), folded into w_q
    const size_t MB = 1024 * 1024;

    // ws (64 MB): Qw@0 16 | Kw@16 16 | Vw@32 16 | Ow@48 16   (all bf16)
    // d_out (32 MB fp32, dead until final GEMM): xb@0 16 | wqkvb@16 6 (bf16).
    // wob (w_out bf16, 2 MB) -> dead Qw region AFTER attn.
    unsigned short* Qw    = (unsigned short*)d_ws;
    unsigned short* Kw    = (unsigned short*)((char*)d_ws + 16 * MB);
    unsigned short* Vw    = (unsigned short*)((char*)d_ws + 32 * MB);
    unsigned short* Ow    = (unsigned short*)((char*)d_ws + 48 * MB);
    unsigned short* xb    = (unsigned short*)d_out;
    unsigned short* wqkvb = (unsigned short*)((char*)d_out + 16 * MB);
    unsigned short* wob   = Qw;

    // Convert x + packed [w_q (pre-scaled); w_kv] to bf16 in d_out scratch.
    convert_regions<<<5632, 256, 0, stream>>>(
        x, xb, 8388608, 1.0f,
        w_q, wqkvb, 1048576, CEXP,
        w_kv, wqkvb + (size_t)1048576, 2097152, 1.0f);

    // Fused QKV projection.
    gemm128<1><<<dim3(64, 24), 256, 0, stream>>>(
        xb, wqkvb, Qw, Kw, Vw, nullptr, 8192, 3072, 1024);

    // Attention: 8 q-blocks x 64 bh = 512 blocks (2/CU).
    attn_kernel<<<dim3(8, 64), 256, 0, stream>>>(Qw, Kw, Vw, Ow);

    // w_out -> bf16 into dead Qw region.
    convert_regions<<<512, 256, 0, stream>>>(
        w_out, wob, 1048576, 1.0f,
        nullptr, nullptr, 0, 0.f, nullptr, nullptr, 0, 0.f);

    // Out projection, all-DMA; writes fp32 d_out (xb/wqkvb scratch dead).
    gemm128<0><<<dim3(64, 8), 256, 0, stream>>>(
        Ow, wob, d_out, nullptr, nullptr, b_out, 8192, 1024, 1024);
}

// Round 9
// 298.933 us; speedup vs baseline: 2.3406x; 2.3406x over previous
//
#include <hip/hip_runtime.h>

typedef __attribute__((ext_vector_type(8))) short bf16x8;
typedef __attribute__((ext_vector_type(4))) float f32x4;

#define AS1 __attribute__((address_space(1)))
#define AS3 __attribute__((address_space(3)))

#if defined(__has_builtin)
#  if __has_builtin(__builtin_amdgcn_exp2f)
#    define EXP2F(x) __builtin_amdgcn_exp2f(x)
#  endif
#endif
#ifndef EXP2F
#  define EXP2F(x) __builtin_exp2f(x)
#endif

__device__ __forceinline__ unsigned short f2bf(float f) {
    union { float f; unsigned u; } v; v.f = f;
    unsigned r = v.u + 0x7fffu + ((v.u >> 16) & 1u);   // RNE
    return (unsigned short)(r >> 16);
}

// Async 16B/lane global->LDS DMA. lds dst must be wave-uniform base (+lane*16).
__device__ __forceinline__ void dma16(const void* g, void* l) {
    __builtin_amdgcn_global_load_lds((const AS1 unsigned int*)g,
                                     (AS3 unsigned int*)l, 16, 0, 0);
}

// fp32 -> bf16 bulk convert, up to 3 regions, optional scale. 8 elems/thread.
__global__ __launch_bounds__(256) void convert_regions(
    const float* __restrict__ s0, unsigned short* __restrict__ d0, int n0, float c0,
    const float* __restrict__ s1, unsigned short* __restrict__ d1, int n1, float c1,
    const float* __restrict__ s2, unsigned short* __restrict__ d2, int n2, float c2)
{
    long long e = ((long long)blockIdx.x * 256 + threadIdx.x) * 8;
    const float* s; unsigned short* d; float sc;
    if (e < n0) { s = s0; d = d0; sc = c0; }
    else { e -= n0;
    if (e < n1) { s = s1; d = d1; sc = c1; }
    else { e -= n1;
    if (e < n2) { s = s2; d = d2; sc = c2; } else return; } }
    const float4 f0 = *(const float4*)(s + e);
    const float4 f1 = *(const float4*)(s + e + 4);
    union { unsigned short u[8]; uint4 q; } t;
    t.u[0]=f2bf(f0.x*sc); t.u[1]=f2bf(f0.y*sc); t.u[2]=f2bf(f0.z*sc); t.u[3]=f2bf(f0.w*sc);
    t.u[4]=f2bf(f1.x*sc); t.u[5]=f2bf(f1.y*sc); t.u[6]=f2bf(f1.z*sc); t.u[7]=f2bf(f1.w*sc);
    *(uint4*)(d + e) = t.q;
}

// ---------------------------------------------------------------------------
// GEMM: C = A[M,K] * B[N,K]^T (+bias). 128x128 tile, BK=64, 4 waves (2x2),
// 4x4 16x16x32 MFMA/wave, bf16 operands via global_load_lds, XOR-swizzled
// unpadded LDS.
// NOTE: NO min-waves launch_bounds — this kernel needs 144 VGPRs; capping to
// 128 or below spills the 64-VGPR accumulator tile (round 8: 3.4x slowdown,
// 2.5 GB of scratch traffic per dispatch).
// CM: 0 = fp32 C0[M,N] + bias.
//     1 = fused QKV epilogue over N=3072: cols 0..1023 -> Q [bh][n][e] (C0),
//         1024..2047 -> K [bh][n][e] (C1), 2048..3071 -> V^T [bh][e][n] (C2).
//         V-blocks compute mfma(bF,aF) (transposed tile) so stores coalesce.
// ---------------------------------------------------------------------------
template<int CM>
__global__ __launch_bounds__(256) void gemm128(
    const unsigned short* __restrict__ A, const unsigned short* __restrict__ B,
    void* __restrict__ C0, void* __restrict__ C1, void* __restrict__ C2,
    const float* __restrict__ bias, int M, int N, int K)
{
    __shared__ __align__(16) unsigned short As[128 * 64];
    __shared__ __align__(16) unsigned short Bs[128 * 64];

    const int tid  = threadIdx.x;
    const int wq   = tid >> 6;
    const int lane = tid & 63;
    const int l16  = lane & 15;
    const int quad = lane >> 4;
    const int m0   = blockIdx.x * 128;
    const int n0   = blockIdx.y * 128;
    const int lr   = lane >> 3;
    const int cs   = lane & 7;
    const bool vswap = (CM == 1) && (n0 >= 2048);

    f32x4 acc[4][4];
#pragma unroll
    for (int mt = 0; mt < 4; ++mt)
#pragma unroll
        for (int nt = 0; nt < 4; ++nt) acc[mt][nt] = (f32x4){0.f, 0.f, 0.f, 0.f};

    for (int kk = 0; kk < K; kk += 64) {
        __syncthreads();
#pragma unroll
        for (int i = 0; i < 4; ++i) {
            const int rr = (wq * 4 + i) * 8 + lr;
            const int cg = cs ^ (rr & 7);
            dma16(A + (size_t)(m0 + rr) * K + kk + cg * 8, As + (wq * 4 + i) * 512);
            dma16(B + (size_t)(n0 + rr) * K + kk + cg * 8, Bs + (wq * 4 + i) * 512);
        }
        __syncthreads();

#pragma unroll
        for (int ch = 0; ch < 2; ++ch) {
            const int swz = (((ch * 4 + quad) ^ (l16 & 7)) * 8);
            bf16x8 aF[4], bF[4];
#pragma unroll
            for (int mt = 0; mt < 4; ++mt)
                aF[mt] = *(const bf16x8*)(As + ((wq >> 1) * 64 + mt * 16 + l16) * 64 + swz);
#pragma unroll
            for (int nt = 0; nt < 4; ++nt)
                bF[nt] = *(const bf16x8*)(Bs + ((wq & 1) * 64 + nt * 16 + l16) * 64 + swz);
            if (vswap) {
#pragma unroll
                for (int mt = 0; mt < 4; ++mt)
#pragma unroll
                    for (int nt = 0; nt < 4; ++nt)
                        acc[mt][nt] = __builtin_amdgcn_mfma_f32_16x16x32_bf16(
                            bF[nt], aF[mt], acc[mt][nt], 0, 0, 0);
            } else {
#pragma unroll
                for (int mt = 0; mt < 4; ++mt)
#pragma unroll
                    for (int nt = 0; nt < 4; ++nt)
                        acc[mt][nt] = __builtin_amdgcn_mfma_f32_16x16x32_bf16(
                            aF[mt], bF[nt], acc[mt][nt], 0, 0, 0);
            }
        }
    }

    const int wr = wq >> 1, wc = wq & 1;
    if (CM == 0) {
#pragma unroll
        for (int mt = 0; mt < 4; ++mt)
#pragma unroll
        for (int nt = 0; nt < 4; ++nt) {
            const int coln = n0 + wc * 64 + nt * 16 + l16;
            const float bv = bias ? bias[coln] : 0.f;
#pragma unroll
            for (int r = 0; r < 4; ++r) {
                const int rowm = m0 + wr * 64 + mt * 16 + quad * 4 + r;
                ((float*)C0)[(size_t)rowm * N + coln] = acc[mt][nt][r] + bv;
            }
        }
    } else if (!vswap) {
        // Q (cols<1024) / K (1024..2047): [bh][n][e]
#pragma unroll
        for (int mt = 0; mt < 4; ++mt)
#pragma unroll
        for (int nt = 0; nt < 4; ++nt) {
            const int coln = n0 + wc * 64 + nt * 16 + l16;
            unsigned short* dst = (coln < 1024) ? (unsigned short*)C0 : (unsigned short*)C1;
            const int h = (coln >> 6) & 15, e = coln & 63;
#pragma unroll
            for (int r = 0; r < 4; ++r) {
                const int rowm = m0 + wr * 64 + mt * 16 + quad * 4 + r;
                const int b = rowm >> 11, n = rowm & 2047;
                dst[(((size_t)(b * 16 + h) * 2048 + n) << 6) + e] = f2bf(acc[mt][nt][r]);
            }
        }
    } else {
        // V^T: acc holds transposed tile; rows = V-cols (e), cols = tokens.
#pragma unroll
        for (int mt = 0; mt < 4; ++mt)
#pragma unroll
        for (int nt = 0; nt < 4; ++nt) {
#pragma unroll
            for (int r = 0; r < 4; ++r) {
                const int eg = n0 + wc * 64 + nt * 16 + quad * 4 + r;  // 2048..3071
                const int h = (eg >> 6) - 32, e = eg & 63;
                const int rowm = m0 + wr * 64 + mt * 16 + l16;
                const int b = rowm >> 11, n = rowm & 2047;
                ((unsigned short*)C2)[((size_t)(b * 16 + h) * 64 + e) * 2048 + n] =
                    f2bf(acc[mt][nt][r]);
            }
        }
    }
}

// ---------------------------------------------------------------------------
// Flash attention. Q,K: [bh][n][e] bf16 (Q pre-scaled by 0.125*log2e);
// V: [bh][e][n] bf16. O: [b*n][1024] bf16.
// Block = 256 q-rows (4 waves x 64 q as 4 sub-tiles of 16): halves K/V
// staging vs 128-q blocks, 262 MFMA-FLOP per staged byte.
// S^T = K*Q^T; raw v_exp_f32; P trunc-packed (v_perm); denom l on the MFMA
// pipe (P x ones); Ps wave-private (no barrier); K/Vt via global_load_lds.
// ---------------------------------------------------------------------------
__global__ __launch_bounds__(256, 2) void attn_kernel(
    const unsigned short* __restrict__ Q, const unsigned short* __restrict__ K,
    const unsigned short* __restrict__ V, unsigned short* __restrict__ O)
{
    __shared__ __align__(16) unsigned short Ks[64 * 64];
    __shared__ __align__(16) unsigned short Vt[64 * 64];
    __shared__ __align__(16) unsigned short Ps[4 * 64 * 72];

    const int tid  = threadIdx.x;
    const int q0   = blockIdx.x * 256;
    const int bh   = blockIdx.y;
    const int wq   = tid >> 6;
    const int lane = tid & 63;
    const int l16  = lane & 15;
    const int quad = lane >> 4;
    const int lr   = lane >> 3;
    const int cs   = lane & 7;

    const unsigned short* Qg = Q + (size_t)bh * 2048 * 64;
    const unsigned short* Kg = K + (size_t)bh * 2048 * 64;
    const unsigned short* Vg = V + (size_t)bh * 64 * 2048;

    bf16x8 bQ[4][2];
#pragma unroll
    for (int sub = 0; sub < 4; ++sub)
#pragma unroll
        for (int ch = 0; ch < 2; ++ch)
            bQ[sub][ch] = *(const bf16x8*)(Qg + (size_t)(q0 + wq * 64 + sub * 16 + l16) * 64
                                           + ch * 32 + quad * 8);

    bf16x8 ones;
#pragma unroll
    for (int i = 0; i < 8; ++i) ones[i] = (short)0x3F80;  // bf16 1.0

    f32x4 o[4][4], lf[4];
#pragma unroll
    for (int s = 0; s < 4; ++s) {
        lf[s] = (f32x4){0.f, 0.f, 0.f, 0.f};
#pragma unroll
        for (int e = 0; e < 4; ++e) o[s][e] = (f32x4){0.f, 0.f, 0.f, 0.f};
    }

    unsigned short* Psw = Ps + wq * 64 * 72;

    for (int kt = 0; kt < 32; ++kt) {
        const int key0 = kt * 64;
        __syncthreads();
#pragma unroll
        for (int i = 0; i < 4; ++i) {
            const int j  = wq * 4 + i;
            const int rr = (j & 7) * 8 + lr;
            const int cg = cs ^ (rr & 7);
            if (j < 8)
                dma16(Kg + (size_t)(key0 + rr) * 64 + cg * 8, Ks + (j & 7) * 512);
            else
                dma16(Vg + (size_t)rr * 2048 + key0 + cg * 8, Vt + (j & 7) * 512);
        }
        __syncthreads();

        // S^T = K Q^T : D[m=key][n=q]  (logits pre-scaled via Q)
        f32x4 s[4][4];
#pragma unroll
        for (int sub = 0; sub < 4; ++sub)
#pragma unroll
            for (int c = 0; c < 4; ++c) s[sub][c] = (f32x4){0.f, 0.f, 0.f, 0.f};
#pragma unroll
        for (int ch = 0; ch < 2; ++ch) {
            const int swz = ((ch * 4 + quad) ^ (l16 & 7)) * 8;
#pragma unroll
            for (int c = 0; c < 4; ++c) {
                const bf16x8 aK = *(const bf16x8*)(Ks + (c * 16 + l16) * 64 + swz);
#pragma unroll
                for (int sub = 0; sub < 4; ++sub)
                    s[sub][c] = __builtin_amdgcn_mfma_f32_16x16x32_bf16(
                        aK, bQ[sub][ch], s[sub][c], 0, 0, 0);
            }
        }

        // p = 2^s (raw v_exp_f32); trunc-pack pairs with v_perm into Ps.
#pragma unroll
        for (int sub = 0; sub < 4; ++sub) {
#pragma unroll
            for (int c = 0; c < 4; ++c) {
                const float p0 = EXP2F(s[sub][c][0]);
                const float p1 = EXP2F(s[sub][c][1]);
                const float p2 = EXP2F(s[sub][c][2]);
                const float p3 = EXP2F(s[sub][c][3]);
                uint2 pk;
                pk.x = __builtin_amdgcn_perm(__float_as_uint(p1), __float_as_uint(p0), 0x07060302);
                pk.y = __builtin_amdgcn_perm(__float_as_uint(p3), __float_as_uint(p2), 0x07060302);
                *(uint2*)(Psw + (sub * 16 + l16) * 72 + c * 16 + quad * 4) = pk;
            }
        }
        // Ps wave-private: compiler lgkmcnt covers RAW; no barrier.

        // O += P V ; l += P 1 (denominator on the MFMA pipe).
#pragma unroll
        for (int cc = 0; cc < 2; ++cc) {
            const int swz = ((cc * 4 + quad) ^ (l16 & 7)) * 8;
            bf16x8 aP[4];
#pragma unroll
            for (int sub = 0; sub < 4; ++sub) {
                aP[sub] = *(const bf16x8*)(Psw + (sub * 16 + l16) * 72 + cc * 32 + quad * 8);
                lf[sub] = __builtin_amdgcn_mfma_f32_16x16x32_bf16(aP[sub], ones, lf[sub], 0, 0, 0);
            }
#pragma unroll
            for (int et = 0; et < 4; ++et) {
                const bf16x8 bV = *(const bf16x8*)(Vt + (et * 16 + l16) * 64 + swz);
#pragma unroll
                for (int sub = 0; sub < 4; ++sub)
                    o[sub][et] = __builtin_amdgcn_mfma_f32_16x16x32_bf16(
                        aP[sub], bV, o[sub][et], 0, 0, 0);
            }
        }
    }

    // l sits in C-layout: lf[sub][r] is the denom for q-row quad*4+r (all l16).
    const int bb = bh >> 4, hh = bh & 15;
#pragma unroll
    for (int sub = 0; sub < 4; ++sub) {
#pragma unroll
        for (int r = 0; r < 4; ++r) {
            const float linv = 1.0f / lf[sub][r];
            const int qrow = q0 + wq * 64 + sub * 16 + quad * 4 + r;
#pragma unroll
            for (int et = 0; et < 4; ++et) {
                O[(size_t)(bb * 2048 + qrow) * 1024 + hh * 64 + et * 16 + l16] =
                    f2bf(o[sub][et][r] * linv);
            }
        }
    }
}

extern "C" void kernel_launch(void* const* d_in, const int* in_sizes, int n_in,
                              void* d_out, int out_size, void* d_ws, size_t ws_size,
                              hipStream_t stream) {
    const float* x     = (const float*)d_in[0];
    const float* w_q   = (const float*)d_in[1];
    const float* w_kv  = (const float*)d_in[2];
    const float* w_out = (const float*)d_in[3];
    const float* b_out = (const float*)d_in[4];
    const float CEXP = 0.125f * 1.44269504f;   // attn scale * log2(e), folded into w_q
    const size_t MB = 1024 * 1024;

    // ws (64 MB): Qw@0 16 | Kw@16 16 | Vw@32 16 | Ow@48 16   (all bf16)
    // d_out (32 MB fp32, dead until final GEMM): xb@0 16 | wqkvb@16 6 (bf16).
    // wob (w_out bf16, 2 MB) -> dead Qw region AFTER attn.
    unsigned short* Qw    = (unsigned short*)d_ws;
    unsigned short* Kw    = (unsigned short*)((char*)d_ws + 16 * MB);
    unsigned short* Vw    = (unsigned short*)((char*)d_ws + 32 * MB);
    unsigned short* Ow    = (unsigned short*)((char*)d_ws + 48 * MB);
    unsigned short* xb    = (unsigned short*)d_out;
    unsigned short* wqkvb = (unsigned short*)((char*)d_out + 16 * MB);
    unsigned short* wob   = Qw;

    // Convert x + packed [w_q (pre-scaled); w_kv] to bf16 in d_out scratch.
    convert_regions<<<5632, 256, 0, stream>>>(
        x, xb, 8388608, 1.0f,
        w_q, wqkvb, 1048576, CEXP,
        w_kv, wqkvb + (size_t)1048576, 2097152, 1.0f);

    // Fused QKV projection.
    gemm128<1><<<dim3(64, 24), 256, 0, stream>>>(
        xb, wqkvb, Qw, Kw, Vw, nullptr, 8192, 3072, 1024);

    // Attention: 8 q-blocks x 64 bh = 512 blocks (2/CU).
    attn_kernel<<<dim3(8, 64), 256, 0, stream>>>(Qw, Kw, Vw, Ow);

    // w_out -> bf16 into dead Qw region.
    convert_regions<<<512, 256, 0, stream>>>(
        w_out, wob, 1048576, 1.0f,
        nullptr, nullptr, 0, 0.f, nullptr, nullptr, 0, 0.f);

    // Out projection, all-DMA; writes fp32 d_out (xb/wqkvb scratch dead).
    gemm128<0><<<dim3(64, 8), 256, 0, stream>>>(
        Ow, wob, d_out, nullptr, nullptr, b_out, 8192, 1024, 1024);
}

// Round 10
// 248.125 us; speedup vs baseline: 2.8199x; 1.2048x over previous
//
#include <hip/hip_runtime.h>

typedef __attribute__((ext_vector_type(8))) short bf16x8;
typedef __attribute__((ext_vector_type(4))) float f32x4;

#define AS1 __attribute__((address_space(1)))
#define AS3 __attribute__((address_space(3)))

#if defined(__has_builtin)
#  if __has_builtin(__builtin_amdgcn_exp2f)
#    define EXP2F(x) __builtin_amdgcn_exp2f(x)
#  endif
#endif
#ifndef EXP2F
#  define EXP2F(x) __builtin_exp2f(x)
#endif

// Raw barriers that do NOT drain the async prefetch queue (unlike __syncthreads,
// which emits s_waitcnt vmcnt(0) lgkmcnt(0) and kills the pipeline).
#define BAR_WAIT_VM8  asm volatile("s_waitcnt vmcnt(8)\ns_barrier" ::: "memory")
#define BAR_WAIT_VM4  asm volatile("s_waitcnt vmcnt(4)\ns_barrier" ::: "memory")
#define BAR_WAIT_VM0  asm volatile("s_waitcnt vmcnt(0)\ns_barrier" ::: "memory")
#define BAR_WAIT_LGKM asm volatile("s_waitcnt lgkmcnt(0)\ns_barrier" ::: "memory")

__device__ __forceinline__ unsigned short f2bf(float f) {
    union { float f; unsigned u; } v; v.f = f;
    unsigned r = v.u + 0x7fffu + ((v.u >> 16) & 1u);   // RNE
    return (unsigned short)(r >> 16);
}

// Async 16B/lane global->LDS DMA. lds dst must be wave-uniform base (+lane*16).
__device__ __forceinline__ void dma16(const void* g, void* l) {
    __builtin_amdgcn_global_load_lds((const AS1 unsigned int*)g,
                                     (AS3 unsigned int*)l, 16, 0, 0);
}

// fp32 -> bf16 bulk convert, up to 3 regions, optional scale. 8 elems/thread.
__global__ __launch_bounds__(256) void convert_regions(
    const float* __restrict__ s0, unsigned short* __restrict__ d0, int n0, float c0,
    const float* __restrict__ s1, unsigned short* __restrict__ d1, int n1, float c1,
    const float* __restrict__ s2, unsigned short* __restrict__ d2, int n2, float c2)
{
    long long e = ((long long)blockIdx.x * 256 + threadIdx.x) * 8;
    const float* s; unsigned short* d; float sc;
    if (e < n0) { s = s0; d = d0; sc = c0; }
    else { e -= n0;
    if (e < n1) { s = s1; d = d1; sc = c1; }
    else { e -= n1;
    if (e < n2) { s = s2; d = d2; sc = c2; } else return; } }
    const float4 f0 = *(const float4*)(s + e);
    const float4 f1 = *(const float4*)(s + e + 4);
    union { unsigned short u[8]; uint4 q; } t;
    t.u[0]=f2bf(f0.x*sc); t.u[1]=f2bf(f0.y*sc); t.u[2]=f2bf(f0.z*sc); t.u[3]=f2bf(f0.w*sc);
    t.u[4]=f2bf(f1.x*sc); t.u[5]=f2bf(f1.y*sc); t.u[6]=f2bf(f1.z*sc); t.u[7]=f2bf(f1.w*sc);
    *(uint4*)(d + e) = t.q;
}

// ---------------------------------------------------------------------------
// GEMM: C = A[M,K] * B[N,K]^T (+bias). 128x128 tile, BK=64, 4 waves (2x2),
// 4x4 16x16x32 MFMA/wave, bf16 operands via global_load_lds, XOR-swizzled
// unpadded LDS. DOUBLE-BUFFERED K-loop with raw-barrier pipeline:
//   top:  issue DMA(tile k+1 -> buf^1); s_waitcnt vmcnt(8); s_barrier
//         (waits only tile k's 8 DMAs; the 8 prefetch DMAs stay in flight)
//   ...compute tile k...
//   end:  s_waitcnt lgkmcnt(0); s_barrier   (read fence, NO vmcnt drain)
// LDS 64 KB -> 2 blocks/CU. NOTE: NO min-waves launch_bounds — needs 144
// VGPRs; capping to <=128 spills the accumulators (round 8: 3.4x slowdown).
// CM: 0 = fp32 C0[M,N] + bias.
//     1 = fused QKV epilogue over N=3072: cols 0..1023 -> Q [bh][n][e] (C0),
//         1024..2047 -> K [bh][n][e] (C1), 2048..3071 -> V^T [bh][e][n] (C2).
//         V-blocks compute mfma(bF,aF) (transposed tile) so stores coalesce.
// ---------------------------------------------------------------------------
template<int CM>
__global__ __launch_bounds__(256) void gemm128(
    const unsigned short* __restrict__ A, const unsigned short* __restrict__ B,
    void* __restrict__ C0, void* __restrict__ C1, void* __restrict__ C2,
    const float* __restrict__ bias, int M, int N, int K)
{
    // [buf][ As 8192 | Bs 8192 ] shorts
    __shared__ __align__(16) unsigned short smem[2 * 16384];

    const int tid  = threadIdx.x;
    const int wq   = tid >> 6;
    const int lane = tid & 63;
    const int l16  = lane & 15;
    const int quad = lane >> 4;
    const int m0   = blockIdx.x * 128;
    const int n0   = blockIdx.y * 128;
    const int lr   = lane >> 3;
    const int cs   = lane & 7;
    const bool vswap = (CM == 1) && (n0 >= 2048);

    f32x4 acc[4][4];
#pragma unroll
    for (int mt = 0; mt < 4; ++mt)
#pragma unroll
        for (int nt = 0; nt < 4; ++nt) acc[mt][nt] = (f32x4){0.f, 0.f, 0.f, 0.f};

    auto issue = [&](int buf, int kk) {
        unsigned short* as = smem + buf * 16384;
        unsigned short* bs = as + 8192;
#pragma unroll
        for (int i = 0; i < 4; ++i) {
            const int rr = (wq * 4 + i) * 8 + lr;
            const int cg = cs ^ (rr & 7);
            dma16(A + (size_t)(m0 + rr) * K + kk + cg * 8, as + (wq * 4 + i) * 512);
            dma16(B + (size_t)(n0 + rr) * K + kk + cg * 8, bs + (wq * 4 + i) * 512);
        }
    };

    const int nIt = K >> 6;
    issue(0, 0);
#pragma unroll 2
    for (int it = 0; it < nIt; ++it) {
        const int cur = it & 1;
        if (it + 1 < nIt) {
            issue(cur ^ 1, (it + 1) << 6);
            BAR_WAIT_VM8;
        } else {
            BAR_WAIT_VM0;
        }
        const unsigned short* as = smem + cur * 16384;
        const unsigned short* bs = as + 8192;
#pragma unroll
        for (int ch = 0; ch < 2; ++ch) {
            const int swz = (((ch * 4 + quad) ^ (l16 & 7)) * 8);
            bf16x8 aF[4], bF[4];
#pragma unroll
            for (int mt = 0; mt < 4; ++mt)
                aF[mt] = *(const bf16x8*)(as + ((wq >> 1) * 64 + mt * 16 + l16) * 64 + swz);
#pragma unroll
            for (int nt = 0; nt < 4; ++nt)
                bF[nt] = *(const bf16x8*)(bs + ((wq & 1) * 64 + nt * 16 + l16) * 64 + swz);
            if (vswap) {
#pragma unroll
                for (int mt = 0; mt < 4; ++mt)
#pragma unroll
                    for (int nt = 0; nt < 4; ++nt)
                        acc[mt][nt] = __builtin_amdgcn_mfma_f32_16x16x32_bf16(
                            bF[nt], aF[mt], acc[mt][nt], 0, 0, 0);
            } else {
#pragma unroll
                for (int mt = 0; mt < 4; ++mt)
#pragma unroll
                    for (int nt = 0; nt < 4; ++nt)
                        acc[mt][nt] = __builtin_amdgcn_mfma_f32_16x16x32_bf16(
                            aF[mt], bF[nt], acc[mt][nt], 0, 0, 0);
            }
        }
        BAR_WAIT_LGKM;
    }

    const int wr = wq >> 1, wc = wq & 1;
    if (CM == 0) {
#pragma unroll
        for (int mt = 0; mt < 4; ++mt)
#pragma unroll
        for (int nt = 0; nt < 4; ++nt) {
            const int coln = n0 + wc * 64 + nt * 16 + l16;
            const float bv = bias ? bias[coln] : 0.f;
#pragma unroll
            for (int r = 0; r < 4; ++r) {
                const int rowm = m0 + wr * 64 + mt * 16 + quad * 4 + r;
                ((float*)C0)[(size_t)rowm * N + coln] = acc[mt][nt][r] + bv;
            }
        }
    } else if (!vswap) {
        // Q (cols<1024) / K (1024..2047): [bh][n][e]
#pragma unroll
        for (int mt = 0; mt < 4; ++mt)
#pragma unroll
        for (int nt = 0; nt < 4; ++nt) {
            const int coln = n0 + wc * 64 + nt * 16 + l16;
            unsigned short* dst = (coln < 1024) ? (unsigned short*)C0 : (unsigned short*)C1;
            const int h = (coln >> 6) & 15, e = coln & 63;
#pragma unroll
            for (int r = 0; r < 4; ++r) {
                const int rowm = m0 + wr * 64 + mt * 16 + quad * 4 + r;
                const int b = rowm >> 11, n = rowm & 2047;
                dst[(((size_t)(b * 16 + h) * 2048 + n) << 6) + e] = f2bf(acc[mt][nt][r]);
            }
        }
    } else {
        // V^T: acc holds transposed tile; rows = V-cols (e), cols = tokens.
#pragma unroll
        for (int mt = 0; mt < 4; ++mt)
#pragma unroll
        for (int nt = 0; nt < 4; ++nt) {
#pragma unroll
            for (int r = 0; r < 4; ++r) {
                const int eg = n0 + wc * 64 + nt * 16 + quad * 4 + r;  // 2048..3071
                const int h = (eg >> 6) - 32, e = eg & 63;
                const int rowm = m0 + wr * 64 + mt * 16 + l16;
                const int b = rowm >> 11, n = rowm & 2047;
                ((unsigned short*)C2)[((size_t)(b * 16 + h) * 64 + e) * 2048 + n] =
                    f2bf(acc[mt][nt][r]);
            }
        }
    }
}

// ---------------------------------------------------------------------------
// Flash attention. Q,K: [bh][n][e] bf16 (Q pre-scaled by 0.125*log2e);
// V: [bh][e][n] bf16. O: [b*n][1024] bf16.
// Block = 256 q-rows (4 waves x 64 q). Same raw-barrier double-buffered K/V
// staging (vmcnt(4) preserves the prefetch tile). S^T = K*Q^T; raw v_exp_f32;
// P trunc-packed (v_perm); denom l on the MFMA pipe (P x ones); Ps
// wave-private. LDS 68.6 KB -> 2 blocks/CU (unchanged).
// ---------------------------------------------------------------------------
__global__ __launch_bounds__(256, 2) void attn_kernel(
    const unsigned short* __restrict__ Q, const unsigned short* __restrict__ K,
    const unsigned short* __restrict__ V, unsigned short* __restrict__ O)
{
    __shared__ __align__(16) unsigned short KVs[2 * 8192];  // [buf][Ks 4096|Vt 4096]
    __shared__ __align__(16) unsigned short Ps[4 * 64 * 72];

    const int tid  = threadIdx.x;
    const int q0   = blockIdx.x * 256;
    const int bh   = blockIdx.y;
    const int wq   = tid >> 6;
    const int lane = tid & 63;
    const int l16  = lane & 15;
    const int quad = lane >> 4;
    const int lr   = lane >> 3;
    const int cs   = lane & 7;

    const unsigned short* Qg = Q + (size_t)bh * 2048 * 64;
    const unsigned short* Kg = K + (size_t)bh * 2048 * 64;
    const unsigned short* Vg = V + (size_t)bh * 64 * 2048;

    bf16x8 bQ[4][2];
#pragma unroll
    for (int sub = 0; sub < 4; ++sub)
#pragma unroll
        for (int ch = 0; ch < 2; ++ch)
            bQ[sub][ch] = *(const bf16x8*)(Qg + (size_t)(q0 + wq * 64 + sub * 16 + l16) * 64
                                           + ch * 32 + quad * 8);

    bf16x8 ones;
#pragma unroll
    for (int i = 0; i < 8; ++i) ones[i] = (short)0x3F80;  // bf16 1.0

    f32x4 o[4][4], lf[4];
#pragma unroll
    for (int s = 0; s < 4; ++s) {
        lf[s] = (f32x4){0.f, 0.f, 0.f, 0.f};
#pragma unroll
        for (int e = 0; e < 4; ++e) o[s][e] = (f32x4){0.f, 0.f, 0.f, 0.f};
    }

    unsigned short* Psw = Ps + wq * 64 * 72;

    auto issueKV = [&](int buf, int key0) {
        unsigned short* ks = KVs + buf * 8192;
        unsigned short* vt = ks + 4096;
#pragma unroll
        for (int i = 0; i < 4; ++i) {
            const int j  = wq * 4 + i;
            const int rr = (j & 7) * 8 + lr;
            const int cg = cs ^ (rr & 7);
            if (j < 8)
                dma16(Kg + (size_t)(key0 + rr) * 64 + cg * 8, ks + (j & 7) * 512);
            else
                dma16(Vg + (size_t)rr * 2048 + key0 + cg * 8, vt + (j & 7) * 512);
        }
    };

    issueKV(0, 0);
#pragma unroll 2
    for (int kt = 0; kt < 32; ++kt) {
        const int cur = kt & 1;
        if (kt + 1 < 32) {
            issueKV(cur ^ 1, (kt + 1) * 64);
            BAR_WAIT_VM4;
        } else {
            BAR_WAIT_VM0;
        }
        const unsigned short* ks = KVs + cur * 8192;
        const unsigned short* vt = ks + 4096;

        // S^T = K Q^T : D[m=key][n=q]  (logits pre-scaled via Q)
        f32x4 s[4][4];
#pragma unroll
        for (int sub = 0; sub < 4; ++sub)
#pragma unroll
            for (int c = 0; c < 4; ++c) s[sub][c] = (f32x4){0.f, 0.f, 0.f, 0.f};
#pragma unroll
        for (int ch = 0; ch < 2; ++ch) {
            const int swz = ((ch * 4 + quad) ^ (l16 & 7)) * 8;
#pragma unroll
            for (int c = 0; c < 4; ++c) {
                const bf16x8 aK = *(const bf16x8*)(ks + (c * 16 + l16) * 64 + swz);
#pragma unroll
                for (int sub = 0; sub < 4; ++sub)
                    s[sub][c] = __builtin_amdgcn_mfma_f32_16x16x32_bf16(
                        aK, bQ[sub][ch], s[sub][c], 0, 0, 0);
            }
        }

        // p = 2^s (raw v_exp_f32); trunc-pack pairs with v_perm into Ps.
#pragma unroll
        for (int sub = 0; sub < 4; ++sub) {
#pragma unroll
            for (int c = 0; c < 4; ++c) {
                const float p0 = EXP2F(s[sub][c][0]);
                const float p1 = EXP2F(s[sub][c][1]);
                const float p2 = EXP2F(s[sub][c][2]);
                const float p3 = EXP2F(s[sub][c][3]);
                uint2 pk;
                pk.x = __builtin_amdgcn_perm(__float_as_uint(p1), __float_as_uint(p0), 0x07060302);
                pk.y = __builtin_amdgcn_perm(__float_as_uint(p3), __float_as_uint(p2), 0x07060302);
                *(uint2*)(Psw + (sub * 16 + l16) * 72 + c * 16 + quad * 4) = pk;
            }
        }
        // Ps wave-private: compiler lgkmcnt covers RAW; no barrier.

        // O += P V ; l += P 1 (denominator on the MFMA pipe).
#pragma unroll
        for (int cc = 0; cc < 2; ++cc) {
            const int swz = ((cc * 4 + quad) ^ (l16 & 7)) * 8;
            bf16x8 aP[4];
#pragma unroll
            for (int sub = 0; sub < 4; ++sub) {
                aP[sub] = *(const bf16x8*)(Psw + (sub * 16 + l16) * 72 + cc * 32 + quad * 8);
                lf[sub] = __builtin_amdgcn_mfma_f32_16x16x32_bf16(aP[sub], ones, lf[sub], 0, 0, 0);
            }
#pragma unroll
            for (int et = 0; et < 4; ++et) {
                const bf16x8 bV = *(const bf16x8*)(vt + (et * 16 + l16) * 64 + swz);
#pragma unroll
                for (int sub = 0; sub < 4; ++sub)
                    o[sub][et] = __builtin_amdgcn_mfma_f32_16x16x32_bf16(
                        aP[sub], bV, o[sub][et], 0, 0, 0);
            }
        }
        BAR_WAIT_LGKM;
    }

    // l sits in C-layout: lf[sub][r] is the denom for q-row quad*4+r (all l16).
    const int bb = bh >> 4, hh = bh & 15;
#pragma unroll
    for (int sub = 0; sub < 4; ++sub) {
#pragma unroll
        for (int r = 0; r < 4; ++r) {
            const float linv = 1.0f / lf[sub][r];
            const int qrow = q0 + wq * 64 + sub * 16 + quad * 4 + r;
#pragma unroll
            for (int et = 0; et < 4; ++et) {
                O[(size_t)(bb * 2048 + qrow) * 1024 + hh * 64 + et * 16 + l16] =
                    f2bf(o[sub][et][r] * linv);
            }
        }
    }
}

extern "C" void kernel_launch(void* const* d_in, const int* in_sizes, int n_in,
                              void* d_out, int out_size, void* d_ws, size_t ws_size,
                              hipStream_t stream) {
    const float* x     = (const float*)d_in[0];
    const float* w_q   = (const float*)d_in[1];
    const float* w_kv  = (const float*)d_in[2];
    const float* w_out = (const float*)d_in[3];
    const float* b_out = (const float*)d_in[4];
    const float CEXP = 0.125f * 1.44269504f;   // attn scale * log2(e), folded into w_q
    const size_t MB = 1024 * 1024;

    // ws (64 MB): Qw@0 16 | Kw@16 16 | Vw@32 16 | Ow@48 16   (all bf16)
    // d_out (32 MB fp32, dead until final GEMM): xb@0 16 | wqkvb@16 6 (bf16).
    // wob (w_out bf16, 2 MB) -> dead Qw region AFTER attn.
    unsigned short* Qw    = (unsigned short*)d_ws;
    unsigned short* Kw    = (unsigned short*)((char*)d_ws + 16 * MB);
    unsigned short* Vw    = (unsigned short*)((char*)d_ws + 32 * MB);
    unsigned short* Ow    = (unsigned short*)((char*)d_ws + 48 * MB);
    unsigned short* xb    = (unsigned short*)d_out;
    unsigned short* wqkvb = (unsigned short*)((char*)d_out + 16 * MB);
    unsigned short* wob   = Qw;

    // Convert x + packed [w_q (pre-scaled); w_kv] to bf16 in d_out scratch.
    convert_regions<<<5632, 256, 0, stream>>>(
        x, xb, 8388608, 1.0f,
        w_q, wqkvb, 1048576, CEXP,
        w_kv, wqkvb + (size_t)1048576, 2097152, 1.0f);

    // Fused QKV projection (double-buffered pipeline).
    gemm128<1><<<dim3(64, 24), 256, 0, stream>>>(
        xb, wqkvb, Qw, Kw, Vw, nullptr, 8192, 3072, 1024);

    // Attention: 8 q-blocks x 64 bh = 512 blocks (2/CU), double-buffered K/V.
    attn_kernel<<<dim3(8, 64), 256, 0, stream>>>(Qw, Kw, Vw, Ow);

    // w_out -> bf16 into dead Qw region.
    convert_regions<<<512, 256, 0, stream>>>(
        w_out, wob, 1048576, 1.0f,
        nullptr, nullptr, 0, 0.f, nullptr, nullptr, 0, 0.f);

    // Out projection, all-DMA, double-buffered; writes fp32 d_out.
    gemm128<0><<<dim3(64, 8), 256, 0, stream>>>(
        Ow, wob, d_out, nullptr, nullptr, b_out, 8192, 1024, 1024);
}